// Round 2
// baseline (149.298 us; speedup 1.0000x reference)
//
#include <hip/hip_runtime.h>
#include <hip/hip_bf16.h>
#include <math.h>

#define ICH   3
#define OCH   16
#define ID    18
#define IH    34
#define IW    34
#define OD    16
#define OH    32
#define OW    32
#define NB    128
#define SPATIAL  (OD * OH * OW)     // 16384 per (b,c)
#define EPSV     1e-5f

typedef __fp16 fp16x2 __attribute__((ext_vector_type(2)));

// Tiny pre-pass: transpose weights [oc][k=81] -> [k=81][oc=16] so the conv's
// per-(ic,kd,kh) weight group (48 floats) is CONTIGUOUS -> 3x s_load_dwordx16
// instead of 48 scattered 4B s_load_dword.
__global__ void transpose_w_kernel(const float* __restrict__ cw,
                                   float* __restrict__ wt) {
    const int i = blockIdx.x * 256 + threadIdx.x;
    if (i < OCH * 81) {
        const int c = i / 81, k = i - c * 81;
        wt[k * OCH + c] = cw[i];
    }
}

// ===== conv v9: compute identical to the 145us baseline (R15 structure).
// ONLY the y store layout changed: channel-last y[b][s][c16] so both the
// conv write and the norm_max read are contiguous (kills the 16-stream
// 32KB power-of-2 stride pattern that camped L2 sets/HBM channels).
// Do NOT: raise min-waves (R2/R3 spill), LDS-stage x (R1-R8), MFMA im2col
// (R13), fp16 x staging (R5), grid caps/fusion (R11), tile shrink (R8).
__global__ __launch_bounds__(256, 2) void conv_stats_kernel(
    const float* __restrict__ x, const float* __restrict__ wt,
    const float* __restrict__ cb, const float* __restrict__ mult,
    unsigned short* __restrict__ y, float* __restrict__ stats)
{
    __shared__ float wsum[4][OCH], wsq[4][OCH];

    const int blk = blockIdx.x;
    const int b = blk >> 4;
    const int d = blk & 15;
    const int tid = threadIdx.x;

    const int h  = tid >> 3;        // 0..31
    const int wq = (tid & 7) << 2;  // 0,4,...,28

    float acc[OCH][4];
#pragma unroll
    for (int c = 0; c < OCH; c++) {
        const float bv = cb[c];
        acc[c][0] = bv; acc[c][1] = bv; acc[c][2] = bv; acc[c][3] = bv;
    }

    for (int ic = 0; ic < ICH; ic++) {
        for (int kd = 0; kd < 3; kd++) {
            const float* plane = x + ((size_t)(b * ICH + ic) * ID + (d + kd)) * (IH * IW);
            const float* wgrp  = wt + (ic * 3 + kd) * 3 * 48;   // 3 kh x 48 floats
#pragma unroll
            for (int kh = 0; kh < 3; kh++) {
                const float* row = plane + (size_t)(h + kh) * IW + wq;
                const float4 v0 = *(const float4*)row;
                const float2 v1 = *(const float2*)(row + 4);
                float in[6];
                in[0] = v0.x; in[1] = v0.y; in[2] = v0.z; in[3] = v0.w;
                in[4] = v1.x; in[5] = v1.y;
                const float* wrow = wgrp + kh * 48;             // contiguous 48
#pragma unroll
                for (int kw = 0; kw < 3; kw++) {
#pragma unroll
                    for (int c = 0; c < OCH; c++) {
                        const float wv = wrow[kw * OCH + c];    // s_load_dwordx16 path
                        acc[c][0] = fmaf(in[kw + 0], wv, acc[c][0]);
                        acc[c][1] = fmaf(in[kw + 1], wv, acc[c][1]);
                        acc[c][2] = fmaf(in[kw + 2], wv, acc[c][2]);
                        acc[c][3] = fmaf(in[kw + 3], wv, acc[c][3]);
                    }
                }
            }
        }
    }

    // ---- multiplier fold + stats (numerics identical to baseline) ----
    float ssum[OCH], ssq[OCH];
#pragma unroll
    for (int c = 0; c < OCH; c++) {
        const float m = mult[c];
        const float o0 = acc[c][0] * m, o1 = acc[c][1] * m;
        const float o2 = acc[c][2] * m, o3 = acc[c][3] * m;
        ssum[c] = (o0 + o1) + (o2 + o3);
        ssq[c]  = (o0 * o0 + o1 * o1) + (o2 * o2 + o3 * o3);
        acc[c][0] = o0; acc[c][1] = o1; acc[c][2] = o2; acc[c][3] = o3;
    }

    // ---- channel-last packed store: y[b][s][c16], 4 positions x 32 B ----
    {
        const int s0 = d * (OH * OW) + h * OW + wq;     // 4 consecutive positions
        unsigned short* yb = y + ((size_t)b * SPATIAL + s0) * OCH;
#pragma unroll
        for (int j = 0; j < 4; j++) {
            union { fp16x2 h; unsigned int u; } pk;
            uint4 q0, q1;
            pk.h = __builtin_amdgcn_cvt_pkrtz(acc[0][j],  acc[1][j]);  q0.x = pk.u;
            pk.h = __builtin_amdgcn_cvt_pkrtz(acc[2][j],  acc[3][j]);  q0.y = pk.u;
            pk.h = __builtin_amdgcn_cvt_pkrtz(acc[4][j],  acc[5][j]);  q0.z = pk.u;
            pk.h = __builtin_amdgcn_cvt_pkrtz(acc[6][j],  acc[7][j]);  q0.w = pk.u;
            pk.h = __builtin_amdgcn_cvt_pkrtz(acc[8][j],  acc[9][j]);  q1.x = pk.u;
            pk.h = __builtin_amdgcn_cvt_pkrtz(acc[10][j], acc[11][j]); q1.y = pk.u;
            pk.h = __builtin_amdgcn_cvt_pkrtz(acc[12][j], acc[13][j]); q1.z = pk.u;
            pk.h = __builtin_amdgcn_cvt_pkrtz(acc[14][j], acc[15][j]); q1.w = pk.u;
            *(uint4*)(yb + (size_t)j * OCH)     = q0;
            *(uint4*)(yb + (size_t)j * OCH + 8) = q1;
        }
    }

    // ---- block reduction of stats, per-block partial write (no atomics) ----
#pragma unroll
    for (int c = 0; c < OCH; c++) {
        for (int off = 32; off > 0; off >>= 1) {
            ssum[c] += __shfl_down(ssum[c], off);
            ssq[c]  += __shfl_down(ssq[c], off);
        }
    }
    const int wave = tid >> 6, lane = tid & 63;
    if (lane == 0) {
#pragma unroll
        for (int c = 0; c < OCH; c++) { wsum[wave][c] = ssum[c]; wsq[wave][c] = ssq[c]; }
    }
    __syncthreads();
    if (tid < OCH) {
        float s = 0.0f, q = 0.0f;
#pragma unroll
        for (int k = 0; k < 4; k++) { s += wsum[k][tid]; q += wsq[k][tid]; }
        const int sbase = ((b * OD + d) * OCH + tid) * 2;
        stats[sbase + 0] = s;
        stats[sbase + 1] = q;
    }
}

// ===== per-(b,c) norm params: {A = rs*m, B = -mean*rs*m, L = -|m|, H = +|m|}
// so the hot kernel does out_c = clamp(v*A + B, L, H) per element.
__global__ void params_kernel(const float* __restrict__ stats,
                              const float* __restrict__ mult,
                              float4* __restrict__ prm)
{
    const int i = blockIdx.x * 256 + threadIdx.x;   // (b,c) pair
    if (i < NB * OCH) {
        const int b = i >> 4, c = i & 15;
        float s = 0.0f, q = 0.0f;
        for (int dd = 0; dd < OD; dd++) {
            s += stats[((b * OD + dd) * OCH + c) * 2 + 0];
            q += stats[((b * OD + dd) * OCH + c) * 2 + 1];
        }
        const float mean = s * (1.0f / (float)SPATIAL);
        float var = q * (1.0f / (float)SPATIAL) - mean * mean;
        var = fmaxf(var, 0.0f);
        const float rs = rsqrtf(var + EPSV);
        const float m  = mult[c];
        float4 p;
        p.x = rs * m;             // A
        p.y = -mean * rs * m;     // B
        p.z = -fabsf(m);          // L
        p.w =  fabsf(m);          // H
        prm[i] = p;
    }
}

// ===== norm_max v3: channel-last y. Each thread: 2 adjacent positions =
// 64 contiguous bytes (4x uint4). Wave footprint fully linear (4 KB).
// No strided streams, no power-of-2 aliasing. Params via wave-uniform
// address -> scalar loads. 4096 blocks.
__global__ __launch_bounds__(256, 4) void norm_max_kernel(
    const unsigned short* __restrict__ y, const float4* __restrict__ prm,
    float* __restrict__ out)
{
    const int blk = blockIdx.x;     // NB*32 = 4096
    const int b   = blk >> 5;
    const int seg = blk & 31;
    const int tid = threadIdx.x;

    const int s = seg * 512 + tid * 2;                   // 2 positions
    const unsigned short* yb = y + ((size_t)b * SPATIAL + s) * OCH;

    const uint4 v0 = *(const uint4*)(yb);        // pos0 ch0-7
    const uint4 v1 = *(const uint4*)(yb + 8);    // pos0 ch8-15
    const uint4 v2 = *(const uint4*)(yb + 16);   // pos1 ch0-7
    const uint4 v3 = *(const uint4*)(yb + 24);   // pos1 ch8-15

    const float4* pb = prm + b * OCH;            // wave-uniform -> s_load
    float A[OCH], Bv[OCH], L[OCH], H[OCH];
#pragma unroll
    for (int c = 0; c < OCH; c++) {
        const float4 p = pb[c];
        A[c] = p.x; Bv[c] = p.y; L[c] = p.z; H[c] = p.w;
    }

    float m0 = -INFINITY, m1 = -INFINITY;

#define DO_PAIR(u_, c0_, mx_)                                              \
    {                                                                      \
        union { unsigned int u; __fp16 h[2]; } a_; a_.u = (u_);            \
        float f0 = fmaf((float)a_.h[0], A[c0_],     Bv[c0_]);              \
        float f1 = fmaf((float)a_.h[1], A[c0_ + 1], Bv[c0_ + 1]);          \
        f0 = fminf(fmaxf(f0, L[c0_]),     H[c0_]);                         \
        f1 = fminf(fmaxf(f1, L[c0_ + 1]), H[c0_ + 1]);                     \
        mx_ = fmaxf(mx_, fmaxf(f0, f1));                                   \
    }

    DO_PAIR(v0.x,  0, m0) DO_PAIR(v0.y,  2, m0)
    DO_PAIR(v0.z,  4, m0) DO_PAIR(v0.w,  6, m0)
    DO_PAIR(v1.x,  8, m0) DO_PAIR(v1.y, 10, m0)
    DO_PAIR(v1.z, 12, m0) DO_PAIR(v1.w, 14, m0)

    DO_PAIR(v2.x,  0, m1) DO_PAIR(v2.y,  2, m1)
    DO_PAIR(v2.z,  4, m1) DO_PAIR(v2.w,  6, m1)
    DO_PAIR(v3.x,  8, m1) DO_PAIR(v3.y, 10, m1)
    DO_PAIR(v3.z, 12, m1) DO_PAIR(v3.w, 14, m1)
#undef DO_PAIR

    float2 o; o.x = m0; o.y = m1;
    *(float2*)&out[(size_t)b * SPATIAL + s] = o;
}

extern "C" void kernel_launch(void* const* d_in, const int* in_sizes, int n_in,
                              void* d_out, int out_size, void* d_ws, size_t ws_size,
                              hipStream_t stream) {
    const float* x    = (const float*)d_in[0];
    const float* cw   = (const float*)d_in[1];
    const float* cb   = (const float*)d_in[2];
    const float* mult = (const float*)d_in[3];
    float* out = (float*)d_out;

    // ws: y fp16 channel-last (64 MB) | stats partials (256 KB) | prm (8 KB) | wt (5.2 KB)
    unsigned short* y = (unsigned short*)d_ws;
    float* stats = (float*)((char*)d_ws + (size_t)NB * OCH * SPATIAL * sizeof(unsigned short));
    float4* prm  = (float4*)(stats + NB * OD * OCH * 2);
    float* wt    = (float*)(prm + NB * OCH);

    transpose_w_kernel<<<6, 256, 0, stream>>>(cw, wt);
    conv_stats_kernel<<<NB * 16, 256, 0, stream>>>(x, wt, cb, mult, y, stats);
    params_kernel<<<8, 256, 0, stream>>>(stats, mult, prm);
    norm_max_kernel<<<NB * 32, 256, 0, stream>>>(y, prm, out);
}